// Round 1
// baseline (1160.164 us; speedup 1.0000x reference)
//
#include <hip/hip_runtime.h>

#define NFEAT 256
#define BN_EPSF 1e-5f
#define SCAN_BS 1024

// ---------------- graph preprocessing ----------------

__global__ void k_count(const int* __restrict__ dst, int* __restrict__ cnt, int E) {
    int i = blockIdx.x * blockDim.x + threadIdx.x;
    if (i < E) atomicAdd(&cnt[dst[i]], 1);
}

__global__ void k_dinv(const int* __restrict__ cnt, float* __restrict__ dinv, int N) {
    int i = blockIdx.x * blockDim.x + threadIdx.x;
    if (i < N) dinv[i] = rsqrtf((float)(cnt[i] + 1));  // +1 self-loop; always >= 1
}

__global__ void k_scan_block(const int* __restrict__ cnt, int* __restrict__ row_ptr,
                             int* __restrict__ blk_sums, int n) {
    __shared__ int sm[SCAN_BS];
    int i = blockIdx.x * SCAN_BS + threadIdx.x;
    int v = (i < n) ? cnt[i] : 0;
    sm[threadIdx.x] = v;
    __syncthreads();
    for (int off = 1; off < SCAN_BS; off <<= 1) {
        int t = (threadIdx.x >= (unsigned)off) ? sm[threadIdx.x - off] : 0;
        __syncthreads();
        sm[threadIdx.x] += t;
        __syncthreads();
    }
    if (i < n) row_ptr[i] = sm[threadIdx.x] - v;  // exclusive prefix
    if (threadIdx.x == SCAN_BS - 1) blk_sums[blockIdx.x] = sm[threadIdx.x];
}

__global__ void k_scan_bsums(int* blk_sums, int nb) {
    if (threadIdx.x == 0 && blockIdx.x == 0) {
        int acc = 0;
        for (int i = 0; i < nb; i++) { int t = blk_sums[i]; blk_sums[i] = acc; acc += t; }
    }
}

__global__ void k_scan_add(int* __restrict__ row_ptr, const int* __restrict__ blk_sums, int n) {
    int i = blockIdx.x * blockDim.x + threadIdx.x;
    if (i < n) row_ptr[i] += blk_sums[i / SCAN_BS];
}

__global__ void k_fill(const int* __restrict__ src, const int* __restrict__ dst,
                       const int* __restrict__ row_ptr, int* __restrict__ cursor,
                       int* __restrict__ csr_src, int E) {
    int i = blockIdx.x * blockDim.x + threadIdx.x;
    if (i < E) {
        int d = dst[i];
        int pos = row_ptr[d] + atomicAdd(&cursor[d], 1);
        csr_src[pos] = src[i];
    }
}

// ---------------- layer 0: aggregate raw x (width 3), then 3->256 matmul ----------------

__global__ void k_agg3(const float* __restrict__ x, const int* __restrict__ csr_src,
                       const int* __restrict__ row_ptr, const int* __restrict__ cnt,
                       const float* __restrict__ dinv, float* __restrict__ agg3, int N) {
    int v = blockIdx.x * blockDim.x + threadIdx.x;
    if (v >= N) return;
    float dv = dinv[v];
    float a0 = dv * dv * x[v * 3 + 0];
    float a1 = dv * dv * x[v * 3 + 1];
    float a2 = dv * dv * x[v * 3 + 2];
    int st = row_ptr[v], len = cnt[v];
    for (int j = 0; j < len; j++) {
        int s = csr_src[st + j];
        float w = dinv[s] * dv;
        a0 += w * x[s * 3 + 0];
        a1 += w * x[s * 3 + 1];
        a2 += w * x[s * 3 + 2];
    }
    agg3[v * 3 + 0] = a0;
    agg3[v * 3 + 1] = a1;
    agg3[v * 3 + 2] = a2;
}

__global__ __launch_bounds__(NFEAT) void k_m0(const float* __restrict__ agg3, const float* __restrict__ W,
                                              const float* __restrict__ b, const float* __restrict__ g,
                                              const float* __restrict__ be, const float* __restrict__ m,
                                              const float* __restrict__ v, float* __restrict__ h, int N) {
    int node = blockIdx.x;
    int c = threadIdx.x;
    if (node >= N) return;
    float a0 = agg3[node * 3 + 0], a1 = agg3[node * 3 + 1], a2 = agg3[node * 3 + 2];
    float acc = a0 * W[c] + a1 * W[NFEAT + c] + a2 * W[2 * NFEAT + c];
    float bn = (acc + b[c] - m[c]) * rsqrtf(v[c] + BN_EPSF) * g[c] + be[c];
    h[node * NFEAT + c] = fmaxf(bn, 0.f);  // layer 0 has ReLU
}

// ---------------- fp32 tiled GEMM: C[M,256] = A[M,256] @ B[256,256] (no bias) ----------------

__global__ __launch_bounds__(256) void k_mm(const float* __restrict__ A, const float* __restrict__ B,
                                            float* __restrict__ C, int M) {
    const int TM = 64, TN = 64, TK = 16;
    __shared__ float As[TK][TM + 1];
    __shared__ float Bs[TK][TN];
    int bm = blockIdx.x * TM, bn = blockIdx.y * TN;
    int tid = threadIdx.x;
    int tm = (tid / 16) * 4, tn = (tid % 16) * 4;
    float acc[4][4] = {};
    for (int k0 = 0; k0 < 256; k0 += TK) {
#pragma unroll
        for (int j = 0; j < 4; j++) {
            int i = tid + 256 * j;
            int r = i / TK, cc = i % TK;
            int gr = bm + r;
            As[cc][r] = (gr < M) ? A[gr * 256 + k0 + cc] : 0.f;
        }
#pragma unroll
        for (int j = 0; j < 4; j++) {
            int i = tid + 256 * j;
            int r = i / TN, cc = i % TN;
            Bs[r][cc] = B[(k0 + r) * 256 + bn + cc];
        }
        __syncthreads();
#pragma unroll
        for (int k = 0; k < TK; k++) {
            float a[4], bb[4];
#pragma unroll
            for (int i = 0; i < 4; i++) a[i] = As[k][tm + i];
#pragma unroll
            for (int i = 0; i < 4; i++) bb[i] = Bs[k][tn + i];
#pragma unroll
            for (int i = 0; i < 4; i++)
#pragma unroll
                for (int j = 0; j < 4; j++) acc[i][j] += a[i] * bb[j];
        }
        __syncthreads();
    }
#pragma unroll
    for (int i = 0; i < 4; i++) {
        int gr = bm + tm + i;
        if (gr < M) {
#pragma unroll
            for (int j = 0; j < 4; j++) C[gr * 256 + bn + tn + j] = acc[i][j];
        }
    }
}

// ---------------- width-256 aggregation with fused BN affine (+optional ReLU) ----------------

template <bool RELU>
__global__ __launch_bounds__(NFEAT) void k_agg256(const float* __restrict__ t, const int* __restrict__ csr_src,
                                                  const int* __restrict__ row_ptr, const int* __restrict__ cnt,
                                                  const float* __restrict__ dinv,
                                                  const float* __restrict__ b, const float* __restrict__ g,
                                                  const float* __restrict__ be, const float* __restrict__ m,
                                                  const float* __restrict__ v, float* __restrict__ out) {
    __shared__ int s_idx[256];
    __shared__ float s_w[256];
    int node = blockIdx.x;
    int c = threadIdx.x;
    float dv = dinv[node];
    float acc = dv * dv * t[node * NFEAT + c];  // self-loop
    int start = row_ptr[node], len = cnt[node];
    for (int base = 0; base < len; base += 256) {
        int chunk = min(256, len - base);
        if (threadIdx.x < (unsigned)chunk) {
            int s = csr_src[start + base + threadIdx.x];
            s_idx[threadIdx.x] = s;
            s_w[threadIdx.x] = dinv[s] * dv;
        }
        __syncthreads();
        for (int j = 0; j < chunk; j++) acc += s_w[j] * t[s_idx[j] * NFEAT + c];
        __syncthreads();
    }
    float bn = (acc + b[c] - m[c]) * rsqrtf(v[c] + BN_EPSF) * g[c] + be[c];
    if (RELU) bn = fmaxf(bn, 0.f);
    out[node * NFEAT + c] = bn;
}

// ---------------- global mean pool ----------------

__global__ __launch_bounds__(NFEAT) void k_pool(const float* __restrict__ h, const int* __restrict__ batch,
                                                float* __restrict__ out, int N) {
    __shared__ int s_se[2];
    int g = blockIdx.x;
    if (threadIdx.x == 0) {
        int lo = 0, hi = N;
        while (lo < hi) { int mid = (lo + hi) >> 1; if (batch[mid] < g) lo = mid + 1; else hi = mid; }
        s_se[0] = lo;
        lo = 0; hi = N;
        while (lo < hi) { int mid = (lo + hi) >> 1; if (batch[mid] < g + 1) lo = mid + 1; else hi = mid; }
        s_se[1] = lo;
    }
    __syncthreads();
    int st = s_se[0], en = s_se[1];
    int c = threadIdx.x;
    float acc = 0.f;
    for (int i = st; i < en; i++) acc += h[i * NFEAT + c];
    float cntf = (float)(en - st);
    out[g * NFEAT + c] = acc / fmaxf(cntf, 1.f);
}

// ---------------- launch ----------------

static inline size_t align_up(size_t x, size_t a) { return (x + a - 1) & ~(a - 1); }

extern "C" void kernel_launch(void* const* d_in, const int* in_sizes, int n_in,
                              void* d_out, int out_size, void* d_ws, size_t ws_size,
                              hipStream_t stream) {
    const float* x = (const float*)d_in[0];
    const int* edge_index = (const int*)d_in[1];
    const int* batch = (const int*)d_in[2];

    const int N = in_sizes[2];          // 50000
    const int E = in_sizes[1] / 2;      // 1600000
    const int G = out_size / NFEAT;     // 64

    const int* e_src = edge_index;
    const int* e_dst = edge_index + E;

    // layer params: d_in[3 + 6*i + {W,b,g,be,m,v}]
    const float* W[3]; const float* bP[3]; const float* gP[3];
    const float* beP[3]; const float* mP[3]; const float* vP[3];
    for (int i = 0; i < 3; i++) {
        W[i]  = (const float*)d_in[3 + 6 * i + 0];
        bP[i] = (const float*)d_in[3 + 6 * i + 1];
        gP[i] = (const float*)d_in[3 + 6 * i + 2];
        beP[i]= (const float*)d_in[3 + 6 * i + 3];
        mP[i] = (const float*)d_in[3 + 6 * i + 4];
        vP[i] = (const float*)d_in[3 + 6 * i + 5];
    }

    // workspace carve-up
    char* ws = (char*)d_ws;
    size_t off = 0;
    auto carve = [&](size_t bytes) { void* p = ws + off; off = align_up(off + bytes, 256); return p; };
    int*   cnt      = (int*)  carve((size_t)N * 4);
    int*   cursor   = (int*)  carve((size_t)N * 4);
    int*   row_ptr  = (int*)  carve((size_t)N * 4);
    int*   blk_sums = (int*)  carve(1024);
    float* dinv     = (float*)carve((size_t)N * 4);
    int*   csr_src  = (int*)  carve((size_t)E * 4);
    float* agg3     = (float*)carve((size_t)N * 3 * 4);
    float* bufA     = (float*)carve((size_t)N * NFEAT * 4);
    float* bufB     = (float*)carve((size_t)N * NFEAT * 4);
    (void)ws_size;

    hipMemsetAsync(cnt, 0, (size_t)N * 4, stream);
    hipMemsetAsync(cursor, 0, (size_t)N * 4, stream);

    const int BS = 256;
    // degree + CSR
    k_count<<<(E + BS - 1) / BS, BS, 0, stream>>>(e_dst, cnt, E);
    k_dinv<<<(N + BS - 1) / BS, BS, 0, stream>>>(cnt, dinv, N);
    int nb = (N + SCAN_BS - 1) / SCAN_BS;
    k_scan_block<<<nb, SCAN_BS, 0, stream>>>(cnt, row_ptr, blk_sums, N);
    k_scan_bsums<<<1, 64, 0, stream>>>(blk_sums, nb);
    k_scan_add<<<(N + BS - 1) / BS, BS, 0, stream>>>(row_ptr, blk_sums, N);
    k_fill<<<(E + BS - 1) / BS, BS, 0, stream>>>(e_src, e_dst, row_ptr, cursor, csr_src, E);

    // layer 0: propagate(x) [width 3] then 3->256 matmul + BN + ReLU
    k_agg3<<<(N + 63) / 64, 64, 0, stream>>>(x, csr_src, row_ptr, cnt, dinv, agg3, N);
    k_m0<<<N, NFEAT, 0, stream>>>(agg3, W[0], bP[0], gP[0], beP[0], mP[0], vP[0], bufA, N);

    dim3 mmGrid((N + 63) / 64, 4);
    // layer 1: h@W1 -> propagate -> BN + ReLU
    k_mm<<<mmGrid, 256, 0, stream>>>(bufA, W[1], bufB, N);
    k_agg256<true><<<N, NFEAT, 0, stream>>>(bufB, csr_src, row_ptr, cnt, dinv,
                                            bP[1], gP[1], beP[1], mP[1], vP[1], bufA);
    // layer 2: h@W2 -> propagate -> BN (no ReLU)
    k_mm<<<mmGrid, 256, 0, stream>>>(bufA, W[2], bufB, N);
    k_agg256<false><<<N, NFEAT, 0, stream>>>(bufB, csr_src, row_ptr, cnt, dinv,
                                             bP[2], gP[2], beP[2], mP[2], vP[2], bufA);

    // pool
    k_pool<<<G, NFEAT, 0, stream>>>(bufA, batch, (float*)d_out, N);
}

// Round 2
// 1012.619 us; speedup vs baseline: 1.1457x; 1.1457x over previous
//
#include <hip/hip_runtime.h>

#define NFEAT 256
#define BN_EPSF 1e-5f
#define SCAN_BS 1024
#define PNODES 128   // nodes per pooling block

// ---------------- graph preprocessing ----------------

__global__ void k_count(const int* __restrict__ dst, int* __restrict__ cnt, int E) {
    int i = blockIdx.x * blockDim.x + threadIdx.x;
    if (i < E) atomicAdd(&cnt[dst[i]], 1);
}

__global__ void k_dinv(const int* __restrict__ cnt, float* __restrict__ dinv, int N) {
    int i = blockIdx.x * blockDim.x + threadIdx.x;
    if (i < N) dinv[i] = rsqrtf((float)(cnt[i] + 1));  // +1 self-loop; always >= 1
}

__global__ void k_scan_block(const int* __restrict__ cnt, int* __restrict__ row_ptr,
                             int* __restrict__ blk_sums, int n) {
    __shared__ int sm[SCAN_BS];
    int i = blockIdx.x * SCAN_BS + threadIdx.x;
    int v = (i < n) ? cnt[i] : 0;
    sm[threadIdx.x] = v;
    __syncthreads();
    for (int off = 1; off < SCAN_BS; off <<= 1) {
        int t = (threadIdx.x >= (unsigned)off) ? sm[threadIdx.x - off] : 0;
        __syncthreads();
        sm[threadIdx.x] += t;
        __syncthreads();
    }
    if (i < n) row_ptr[i] = sm[threadIdx.x] - v;  // exclusive prefix
    if (threadIdx.x == SCAN_BS - 1) blk_sums[blockIdx.x] = sm[threadIdx.x];
}

__global__ void k_scan_bsums(int* blk_sums, int nb) {
    if (threadIdx.x == 0 && blockIdx.x == 0) {
        int acc = 0;
        for (int i = 0; i < nb; i++) { int t = blk_sums[i]; blk_sums[i] = acc; acc += t; }
    }
}

__global__ void k_scan_add(int* __restrict__ row_ptr, const int* __restrict__ blk_sums, int n) {
    int i = blockIdx.x * blockDim.x + threadIdx.x;
    if (i < n) row_ptr[i] += blk_sums[i / SCAN_BS];
}

__global__ void k_fill(const int* __restrict__ src, const int* __restrict__ dst,
                       const int* __restrict__ row_ptr, int* __restrict__ cursor,
                       int* __restrict__ csr_src, int E) {
    int i = blockIdx.x * blockDim.x + threadIdx.x;
    if (i < E) {
        int d = dst[i];
        int pos = row_ptr[d] + atomicAdd(&cursor[d], 1);
        csr_src[pos] = src[i];
    }
}

// ---------------- layer 0: aggregate raw x (width 3), then 3->256 matmul ----------------

__global__ void k_agg3(const float* __restrict__ x, const int* __restrict__ csr_src,
                       const int* __restrict__ row_ptr, const int* __restrict__ cnt,
                       const float* __restrict__ dinv, float* __restrict__ agg3, int N) {
    int v = blockIdx.x * blockDim.x + threadIdx.x;
    if (v >= N) return;
    float dv = dinv[v];
    float a0 = dv * dv * x[v * 3 + 0];
    float a1 = dv * dv * x[v * 3 + 1];
    float a2 = dv * dv * x[v * 3 + 2];
    int st = row_ptr[v], len = cnt[v];
    for (int j = 0; j < len; j++) {
        int s = csr_src[st + j];
        float w = dinv[s] * dv;
        a0 += w * x[s * 3 + 0];
        a1 += w * x[s * 3 + 1];
        a2 += w * x[s * 3 + 2];
    }
    agg3[v * 3 + 0] = a0;
    agg3[v * 3 + 1] = a1;
    agg3[v * 3 + 2] = a2;
}

__global__ __launch_bounds__(NFEAT) void k_m0(const float* __restrict__ agg3, const float* __restrict__ W,
                                              const float* __restrict__ b, const float* __restrict__ g,
                                              const float* __restrict__ be, const float* __restrict__ m,
                                              const float* __restrict__ v, float* __restrict__ h, int N) {
    int node = blockIdx.x;
    int c = threadIdx.x;
    if (node >= N) return;
    float a0 = agg3[node * 3 + 0], a1 = agg3[node * 3 + 1], a2 = agg3[node * 3 + 2];
    float acc = a0 * W[c] + a1 * W[NFEAT + c] + a2 * W[2 * NFEAT + c];
    float bn = (acc + b[c] - m[c]) * rsqrtf(v[c] + BN_EPSF) * g[c] + be[c];
    h[node * NFEAT + c] = fmaxf(bn, 0.f);  // layer 0 has ReLU
}

// ---------------- fp32 tiled GEMM: C[M,256] = A[M,256] @ B[256,256] (no bias) ----------------

__global__ __launch_bounds__(256) void k_mm(const float* __restrict__ A, const float* __restrict__ B,
                                            float* __restrict__ C, int M) {
    const int TM = 64, TN = 64, TK = 16;
    __shared__ float As[TK][TM + 1];
    __shared__ float Bs[TK][TN];
    int bm = blockIdx.x * TM, bn = blockIdx.y * TN;
    int tid = threadIdx.x;
    int tm = (tid / 16) * 4, tn = (tid % 16) * 4;
    float acc[4][4] = {};
    for (int k0 = 0; k0 < 256; k0 += TK) {
#pragma unroll
        for (int j = 0; j < 4; j++) {
            int i = tid + 256 * j;
            int r = i / TK, cc = i % TK;
            int gr = bm + r;
            As[cc][r] = (gr < M) ? A[gr * 256 + k0 + cc] : 0.f;
        }
#pragma unroll
        for (int j = 0; j < 4; j++) {
            int i = tid + 256 * j;
            int r = i / TN, cc = i % TN;
            Bs[r][cc] = B[(k0 + r) * 256 + bn + cc];
        }
        __syncthreads();
#pragma unroll
        for (int k = 0; k < TK; k++) {
            float a[4], bb[4];
#pragma unroll
            for (int i = 0; i < 4; i++) a[i] = As[k][tm + i];
#pragma unroll
            for (int i = 0; i < 4; i++) bb[i] = Bs[k][tn + i];
#pragma unroll
            for (int i = 0; i < 4; i++)
#pragma unroll
                for (int j = 0; j < 4; j++) acc[i][j] += a[i] * bb[j];
        }
        __syncthreads();
    }
#pragma unroll
    for (int i = 0; i < 4; i++) {
        int gr = bm + tm + i;
        if (gr < M) {
#pragma unroll
            for (int j = 0; j < 4; j++) C[gr * 256 + bn + tn + j] = acc[i][j];
        }
    }
}

// ---------------- width-256 aggregation with fused BN affine (+optional ReLU) ----------------

template <bool RELU>
__global__ __launch_bounds__(NFEAT) void k_agg256(const float* __restrict__ t, const int* __restrict__ csr_src,
                                                  const int* __restrict__ row_ptr, const int* __restrict__ cnt,
                                                  const float* __restrict__ dinv,
                                                  const float* __restrict__ b, const float* __restrict__ g,
                                                  const float* __restrict__ be, const float* __restrict__ m,
                                                  const float* __restrict__ v, float* __restrict__ out) {
    __shared__ int s_idx[256];
    __shared__ float s_w[256];
    int node = blockIdx.x;
    int c = threadIdx.x;
    float dv = dinv[node];
    float acc = dv * dv * t[node * NFEAT + c];  // self-loop
    int start = row_ptr[node], len = cnt[node];
    for (int base = 0; base < len; base += 256) {
        int chunk = min(256, len - base);
        if (threadIdx.x < (unsigned)chunk) {
            int s = csr_src[start + base + threadIdx.x];
            s_idx[threadIdx.x] = s;
            s_w[threadIdx.x] = dinv[s] * dv;
        }
        __syncthreads();
        for (int j = 0; j < chunk; j++) acc += s_w[j] * t[s_idx[j] * NFEAT + c];
        __syncthreads();
    }
    float bn = (acc + b[c] - m[c]) * rsqrtf(v[c] + BN_EPSF) * g[c] + be[c];
    if (RELU) bn = fmaxf(bn, 0.f);
    out[node * NFEAT + c] = bn;
}

// ---------------- global mean pool (two-stage, parallel) ----------------
// Stage 1: each block reduces PNODES consecutive nodes; batch is sorted so a
// slice spans few graphs -> few atomicAdd flushes into zeroed sums buffer.

__global__ __launch_bounds__(NFEAT) void k_pool_partial(const float* __restrict__ h,
                                                        const int* __restrict__ batch,
                                                        float* __restrict__ sums, int N) {
    __shared__ int s_batch[PNODES];
    int i0 = blockIdx.x * PNODES;
    int i1 = min(N, i0 + PNODES);
    int len = i1 - i0;
    if (threadIdx.x < (unsigned)len) s_batch[threadIdx.x] = batch[i0 + threadIdx.x];
    __syncthreads();
    int c = threadIdx.x;
    float acc = 0.f;
    int cur = s_batch[0];
    for (int j = 0; j < len; j++) {
        int g = s_batch[j];
        if (g != cur) {
            atomicAdd(&sums[cur * NFEAT + c], acc);
            acc = 0.f;
            cur = g;
        }
        acc += h[(i0 + j) * NFEAT + c];
    }
    atomicAdd(&sums[cur * NFEAT + c], acc);
}

// Stage 2: divide by per-graph node count (binary search over sorted batch).

__global__ __launch_bounds__(NFEAT) void k_pool_final(const float* __restrict__ sums,
                                                      const int* __restrict__ batch,
                                                      float* __restrict__ out, int N) {
    __shared__ int s_se[2];
    int g = blockIdx.x;
    if (threadIdx.x == 0) {
        int lo = 0, hi = N;
        while (lo < hi) { int mid = (lo + hi) >> 1; if (batch[mid] < g) lo = mid + 1; else hi = mid; }
        s_se[0] = lo;
        lo = 0; hi = N;
        while (lo < hi) { int mid = (lo + hi) >> 1; if (batch[mid] < g + 1) lo = mid + 1; else hi = mid; }
        s_se[1] = lo;
    }
    __syncthreads();
    float cntf = (float)(s_se[1] - s_se[0]);
    int c = threadIdx.x;
    out[g * NFEAT + c] = sums[g * NFEAT + c] / fmaxf(cntf, 1.f);
}

// ---------------- launch ----------------

static inline size_t align_up(size_t x, size_t a) { return (x + a - 1) & ~(a - 1); }

extern "C" void kernel_launch(void* const* d_in, const int* in_sizes, int n_in,
                              void* d_out, int out_size, void* d_ws, size_t ws_size,
                              hipStream_t stream) {
    const float* x = (const float*)d_in[0];
    const int* edge_index = (const int*)d_in[1];
    const int* batch = (const int*)d_in[2];

    const int N = in_sizes[2];          // 50000
    const int E = in_sizes[1] / 2;      // 1600000
    const int G = out_size / NFEAT;     // 64

    const int* e_src = edge_index;
    const int* e_dst = edge_index + E;

    // layer params: d_in[3 + 6*i + {W,b,g,be,m,v}]
    const float* W[3]; const float* bP[3]; const float* gP[3];
    const float* beP[3]; const float* mP[3]; const float* vP[3];
    for (int i = 0; i < 3; i++) {
        W[i]  = (const float*)d_in[3 + 6 * i + 0];
        bP[i] = (const float*)d_in[3 + 6 * i + 1];
        gP[i] = (const float*)d_in[3 + 6 * i + 2];
        beP[i]= (const float*)d_in[3 + 6 * i + 3];
        mP[i] = (const float*)d_in[3 + 6 * i + 4];
        vP[i] = (const float*)d_in[3 + 6 * i + 5];
    }

    // workspace carve-up
    char* ws = (char*)d_ws;
    size_t off = 0;
    auto carve = [&](size_t bytes) { void* p = ws + off; off = align_up(off + bytes, 256); return p; };
    int*   cnt      = (int*)  carve((size_t)N * 4);
    int*   cursor   = (int*)  carve((size_t)N * 4);
    int*   row_ptr  = (int*)  carve((size_t)N * 4);
    int*   blk_sums = (int*)  carve(1024);
    float* dinv     = (float*)carve((size_t)N * 4);
    int*   csr_src  = (int*)  carve((size_t)E * 4);
    float* agg3     = (float*)carve((size_t)N * 3 * 4);
    float* bufA     = (float*)carve((size_t)N * NFEAT * 4);
    float* bufB     = (float*)carve((size_t)N * NFEAT * 4);
    float* psums    = (float*)carve((size_t)G * NFEAT * 4);
    (void)ws_size;

    hipMemsetAsync(cnt, 0, (size_t)N * 4, stream);
    hipMemsetAsync(cursor, 0, (size_t)N * 4, stream);
    hipMemsetAsync(psums, 0, (size_t)G * NFEAT * 4, stream);

    const int BS = 256;
    // degree + CSR
    k_count<<<(E + BS - 1) / BS, BS, 0, stream>>>(e_dst, cnt, E);
    k_dinv<<<(N + BS - 1) / BS, BS, 0, stream>>>(cnt, dinv, N);
    int nb = (N + SCAN_BS - 1) / SCAN_BS;
    k_scan_block<<<nb, SCAN_BS, 0, stream>>>(cnt, row_ptr, blk_sums, N);
    k_scan_bsums<<<1, 64, 0, stream>>>(blk_sums, nb);
    k_scan_add<<<(N + BS - 1) / BS, BS, 0, stream>>>(row_ptr, blk_sums, N);
    k_fill<<<(E + BS - 1) / BS, BS, 0, stream>>>(e_src, e_dst, row_ptr, cursor, csr_src, E);

    // layer 0: propagate(x) [width 3] then 3->256 matmul + BN + ReLU
    k_agg3<<<(N + 63) / 64, 64, 0, stream>>>(x, csr_src, row_ptr, cnt, dinv, agg3, N);
    k_m0<<<N, NFEAT, 0, stream>>>(agg3, W[0], bP[0], gP[0], beP[0], mP[0], vP[0], bufA, N);

    dim3 mmGrid((N + 63) / 64, 4);
    // layer 1: h@W1 -> propagate -> BN + ReLU
    k_mm<<<mmGrid, 256, 0, stream>>>(bufA, W[1], bufB, N);
    k_agg256<true><<<N, NFEAT, 0, stream>>>(bufB, csr_src, row_ptr, cnt, dinv,
                                            bP[1], gP[1], beP[1], mP[1], vP[1], bufA);
    // layer 2: h@W2 -> propagate -> BN (no ReLU)
    k_mm<<<mmGrid, 256, 0, stream>>>(bufA, W[2], bufB, N);
    k_agg256<false><<<N, NFEAT, 0, stream>>>(bufB, csr_src, row_ptr, cnt, dinv,
                                             bP[2], gP[2], beP[2], mP[2], vP[2], bufA);

    // pool: parallel two-stage
    int pb = (N + PNODES - 1) / PNODES;
    k_pool_partial<<<pb, NFEAT, 0, stream>>>(bufA, batch, psums, N);
    k_pool_final<<<G, NFEAT, 0, stream>>>(psums, batch, (float*)d_out, N);
}

// Round 3
// 616.270 us; speedup vs baseline: 1.8826x; 1.6431x over previous
//
#include <hip/hip_runtime.h>

#define NFEAT 256
#define BN_EPSF 1e-5f
#define SCAN_BS 1024
#define PNODES 128   // nodes per pooling block

typedef __attribute__((ext_vector_type(8))) short bf16x8;
typedef __attribute__((ext_vector_type(4))) float f32x4;

__device__ __forceinline__ unsigned short f2bf(float f) {
    union { float f; unsigned u; } v; v.f = f;
    unsigned r = v.u + 0x7fffu + ((v.u >> 16) & 1u);  // round-to-nearest-even
    return (unsigned short)(r >> 16);
}
__device__ __forceinline__ float bf2f(unsigned short h) {
    union { unsigned u; float f; } v; v.u = ((unsigned)h) << 16;
    return v.f;
}

// ---------------- graph preprocessing ----------------

__global__ void k_count(const int* __restrict__ dst, int* __restrict__ cnt, int E) {
    int i = blockIdx.x * blockDim.x + threadIdx.x;
    if (i < E) atomicAdd(&cnt[dst[i]], 1);
}

__global__ void k_dinv(const int* __restrict__ cnt, float* __restrict__ dinv, int N) {
    int i = blockIdx.x * blockDim.x + threadIdx.x;
    if (i < N) dinv[i] = rsqrtf((float)(cnt[i] + 1));  // +1 self-loop; always >= 1
}

__global__ void k_scan_block(const int* __restrict__ cnt, int* __restrict__ row_ptr,
                             int* __restrict__ blk_sums, int n) {
    __shared__ int sm[SCAN_BS];
    int i = blockIdx.x * SCAN_BS + threadIdx.x;
    int v = (i < n) ? cnt[i] : 0;
    sm[threadIdx.x] = v;
    __syncthreads();
    for (int off = 1; off < SCAN_BS; off <<= 1) {
        int t = (threadIdx.x >= (unsigned)off) ? sm[threadIdx.x - off] : 0;
        __syncthreads();
        sm[threadIdx.x] += t;
        __syncthreads();
    }
    if (i < n) row_ptr[i] = sm[threadIdx.x] - v;  // exclusive prefix
    if (threadIdx.x == SCAN_BS - 1) blk_sums[blockIdx.x] = sm[threadIdx.x];
}

__global__ void k_scan_bsums(int* blk_sums, int nb) {
    if (threadIdx.x == 0 && blockIdx.x == 0) {
        int acc = 0;
        for (int i = 0; i < nb; i++) { int t = blk_sums[i]; blk_sums[i] = acc; acc += t; }
    }
}

__global__ void k_scan_add(int* __restrict__ row_ptr, const int* __restrict__ blk_sums, int n) {
    int i = blockIdx.x * blockDim.x + threadIdx.x;
    if (i < n) row_ptr[i] += blk_sums[i / SCAN_BS];
}

__global__ void k_fill(const int* __restrict__ src, const int* __restrict__ dst,
                       const int* __restrict__ row_ptr, int* __restrict__ cursor,
                       int* __restrict__ csr_src, int E) {
    int i = blockIdx.x * blockDim.x + threadIdx.x;
    if (i < E) {
        int d = dst[i];
        int pos = row_ptr[d] + atomicAdd(&cursor[d], 1);
        csr_src[pos] = src[i];
    }
}

// ---------------- weight transpose + bf16 convert: Wt[n][k] = W[k][n] ----------------

__global__ __launch_bounds__(256) void k_wconv(const float* __restrict__ W, unsigned short* __restrict__ Wt) {
    int k = blockIdx.x, n = threadIdx.x;
    Wt[n * 256 + k] = f2bf(W[k * 256 + n]);
}

// ---------------- layer 0: aggregate raw x (width 3), then 3->256 matmul ----------------

__global__ void k_agg3(const float* __restrict__ x, const int* __restrict__ csr_src,
                       const int* __restrict__ row_ptr, const int* __restrict__ cnt,
                       const float* __restrict__ dinv, float* __restrict__ agg3, int N) {
    int v = blockIdx.x * blockDim.x + threadIdx.x;
    if (v >= N) return;
    float dv = dinv[v];
    float a0 = dv * dv * x[v * 3 + 0];
    float a1 = dv * dv * x[v * 3 + 1];
    float a2 = dv * dv * x[v * 3 + 2];
    int st = row_ptr[v], len = cnt[v];
    for (int j = 0; j < len; j++) {
        int s = csr_src[st + j];
        float w = dinv[s] * dv;
        a0 += w * x[s * 3 + 0];
        a1 += w * x[s * 3 + 1];
        a2 += w * x[s * 3 + 2];
    }
    agg3[v * 3 + 0] = a0;
    agg3[v * 3 + 1] = a1;
    agg3[v * 3 + 2] = a2;
}

__global__ __launch_bounds__(NFEAT) void k_m0(const float* __restrict__ agg3, const float* __restrict__ W,
                                              const float* __restrict__ b, const float* __restrict__ g,
                                              const float* __restrict__ be, const float* __restrict__ m,
                                              const float* __restrict__ v, unsigned short* __restrict__ h, int N) {
    int node = blockIdx.x;
    int c = threadIdx.x;
    if (node >= N) return;
    float a0 = agg3[node * 3 + 0], a1 = agg3[node * 3 + 1], a2 = agg3[node * 3 + 2];
    float acc = a0 * W[c] + a1 * W[NFEAT + c] + a2 * W[2 * NFEAT + c];
    float bn = (acc + b[c] - m[c]) * rsqrtf(v[c] + BN_EPSF) * g[c] + be[c];
    h[node * NFEAT + c] = f2bf(fmaxf(bn, 0.f));  // layer 0 has ReLU
}

// ---------------- bf16 MFMA GEMM: C[M,256] = A[M,256] @ B[256,256] ----------------
// A bf16 row-major, Bt bf16 pre-transposed (Bt[n][k] = B[k][n]), C bf16.
// BM=BN=128, BK=32; 256 threads = 2x2 waves of 64x64; 16x16x32 bf16 MFMA.
// Fragment layouts (HW-verified, guide §3): A[m=lane&15][k=(lane>>4)*8+j];
// B[k=(lane>>4)*8+j][n=lane&15]; C/D row=(lane>>4)*4+reg, col=lane&15.

__global__ __launch_bounds__(256) void k_mm_mfma(const unsigned short* __restrict__ A,
                                                 const unsigned short* __restrict__ Bt,
                                                 unsigned short* __restrict__ C, int M) {
    __shared__ __align__(16) unsigned short As[4][128][8];  // [kchunk][row][j] 8KB
    __shared__ __align__(16) unsigned short Bs[4][128][8];  // [kchunk][col][j] 8KB
    int bm = blockIdx.x * 128, bn = blockIdx.y * 128;
    int tid = threadIdx.x;
    int lane = tid & 63, wave = tid >> 6;
    int wm = (wave & 1) * 64, wn = (wave >> 1) * 64;
    int lrow = lane & 15, lk = lane >> 4;
    f32x4 acc[4][4] = {};

    for (int k0 = 0; k0 < 256; k0 += 32) {
        // stage: 512 chunks of 16B; ch = idx&3 so 4 adjacent lanes read 64B contiguous
#pragma unroll
        for (int i = 0; i < 2; i++) {
            int idx = tid + 256 * i;
            int ch = idx & 3, row = idx >> 2;
            int gr = bm + row;
            uint4 va = {0u, 0u, 0u, 0u};
            if (gr < M) va = *(const uint4*)(A + (size_t)gr * 256 + k0 + ch * 8);
            *(uint4*)(&As[ch][row][0]) = va;
            uint4 vb = *(const uint4*)(Bt + (size_t)(bn + row) * 256 + k0 + ch * 8);
            *(uint4*)(&Bs[ch][row][0]) = vb;
        }
        __syncthreads();
        bf16x8 af[4], bf[4];
#pragma unroll
        for (int r = 0; r < 4; r++) af[r] = *(const bf16x8*)(&As[lk][wm + r * 16 + lrow][0]);
#pragma unroll
        for (int c = 0; c < 4; c++) bf[c] = *(const bf16x8*)(&Bs[lk][wn + c * 16 + lrow][0]);
#pragma unroll
        for (int r = 0; r < 4; r++)
#pragma unroll
            for (int c = 0; c < 4; c++)
                acc[r][c] = __builtin_amdgcn_mfma_f32_16x16x32_bf16(af[r], bf[c], acc[r][c], 0, 0, 0);
        __syncthreads();
    }

#pragma unroll
    for (int r = 0; r < 4; r++) {
#pragma unroll
        for (int reg = 0; reg < 4; reg++) {
            int grow = bm + wm + r * 16 + lk * 4 + reg;
            if (grow < M) {
#pragma unroll
                for (int c = 0; c < 4; c++) {
                    int gcol = bn + wn + c * 16 + lrow;
                    C[(size_t)grow * 256 + gcol] = f2bf(acc[r][c][reg]);
                }
            }
        }
    }
}

// ---------------- bf16 aggregation with fused BN affine (+optional ReLU) ----------------
// One wave per node; lane owns 4 channels (ushort4 = 8B loads).

template <bool RELU>
__global__ __launch_bounds__(64) void k_agg256b(const unsigned short* __restrict__ t,
                                                const int* __restrict__ csr_src,
                                                const int* __restrict__ row_ptr, const int* __restrict__ cnt,
                                                const float* __restrict__ dinv,
                                                const float* __restrict__ b, const float* __restrict__ g,
                                                const float* __restrict__ be, const float* __restrict__ m,
                                                const float* __restrict__ v, unsigned short* __restrict__ out) {
    __shared__ int s_idx[64];
    __shared__ float s_w[64];
    int node = blockIdx.x;
    int c4 = threadIdx.x * 4;
    float dv = dinv[node];
    float a0, a1, a2, a3;
    {
        ushort4 u = *(const ushort4*)(t + (size_t)node * NFEAT + c4);
        float w = dv * dv;
        a0 = w * bf2f(u.x); a1 = w * bf2f(u.y); a2 = w * bf2f(u.z); a3 = w * bf2f(u.w);
    }
    int start = row_ptr[node], len = cnt[node];
    for (int base = 0; base < len; base += 64) {
        int chunk = min(64, len - base);
        if ((int)threadIdx.x < chunk) {
            int s = csr_src[start + base + threadIdx.x];
            s_idx[threadIdx.x] = s;
            s_w[threadIdx.x] = dinv[s] * dv;
        }
        __syncthreads();
        int j = 0;
        for (; j + 4 <= chunk; j += 4) {
            ushort4 u0 = *(const ushort4*)(t + (size_t)s_idx[j + 0] * NFEAT + c4);
            ushort4 u1 = *(const ushort4*)(t + (size_t)s_idx[j + 1] * NFEAT + c4);
            ushort4 u2 = *(const ushort4*)(t + (size_t)s_idx[j + 2] * NFEAT + c4);
            ushort4 u3 = *(const ushort4*)(t + (size_t)s_idx[j + 3] * NFEAT + c4);
            float w0 = s_w[j + 0], w1 = s_w[j + 1], w2 = s_w[j + 2], w3 = s_w[j + 3];
            a0 += w0 * bf2f(u0.x); a1 += w0 * bf2f(u0.y); a2 += w0 * bf2f(u0.z); a3 += w0 * bf2f(u0.w);
            a0 += w1 * bf2f(u1.x); a1 += w1 * bf2f(u1.y); a2 += w1 * bf2f(u1.z); a3 += w1 * bf2f(u1.w);
            a0 += w2 * bf2f(u2.x); a1 += w2 * bf2f(u2.y); a2 += w2 * bf2f(u2.z); a3 += w2 * bf2f(u2.w);
            a0 += w3 * bf2f(u3.x); a1 += w3 * bf2f(u3.y); a2 += w3 * bf2f(u3.z); a3 += w3 * bf2f(u3.w);
        }
        for (; j < chunk; j++) {
            ushort4 u = *(const ushort4*)(t + (size_t)s_idx[j] * NFEAT + c4);
            float w = s_w[j];
            a0 += w * bf2f(u.x); a1 += w * bf2f(u.y); a2 += w * bf2f(u.z); a3 += w * bf2f(u.w);
        }
        __syncthreads();
    }
    float4 bb = *(const float4*)(b + c4);
    float4 gg = *(const float4*)(g + c4);
    float4 ee = *(const float4*)(be + c4);
    float4 mm = *(const float4*)(m + c4);
    float4 vv = *(const float4*)(v + c4);
    float r0 = (a0 + bb.x - mm.x) * rsqrtf(vv.x + BN_EPSF) * gg.x + ee.x;
    float r1 = (a1 + bb.y - mm.y) * rsqrtf(vv.y + BN_EPSF) * gg.y + ee.y;
    float r2 = (a2 + bb.z - mm.z) * rsqrtf(vv.z + BN_EPSF) * gg.z + ee.z;
    float r3 = (a3 + bb.w - mm.w) * rsqrtf(vv.w + BN_EPSF) * gg.w + ee.w;
    if (RELU) { r0 = fmaxf(r0, 0.f); r1 = fmaxf(r1, 0.f); r2 = fmaxf(r2, 0.f); r3 = fmaxf(r3, 0.f); }
    ushort4 o; o.x = f2bf(r0); o.y = f2bf(r1); o.z = f2bf(r2); o.w = f2bf(r3);
    *(ushort4*)(out + (size_t)node * NFEAT + c4) = o;
}

// ---------------- global mean pool (two-stage, parallel) ----------------

__global__ __launch_bounds__(NFEAT) void k_pool_partial(const unsigned short* __restrict__ h,
                                                        const int* __restrict__ batch,
                                                        float* __restrict__ sums, int N) {
    __shared__ int s_batch[PNODES];
    int i0 = blockIdx.x * PNODES;
    int i1 = min(N, i0 + PNODES);
    int len = i1 - i0;
    if (threadIdx.x < (unsigned)len) s_batch[threadIdx.x] = batch[i0 + threadIdx.x];
    __syncthreads();
    int c = threadIdx.x;
    float acc = 0.f;
    int cur = s_batch[0];
    for (int j = 0; j < len; j++) {
        int g = s_batch[j];
        if (g != cur) {
            atomicAdd(&sums[cur * NFEAT + c], acc);
            acc = 0.f;
            cur = g;
        }
        acc += bf2f(h[(size_t)(i0 + j) * NFEAT + c]);
    }
    atomicAdd(&sums[cur * NFEAT + c], acc);
}

__global__ __launch_bounds__(NFEAT) void k_pool_final(const float* __restrict__ sums,
                                                      const int* __restrict__ batch,
                                                      float* __restrict__ out, int N) {
    __shared__ int s_se[2];
    int g = blockIdx.x;
    if (threadIdx.x == 0) {
        int lo = 0, hi = N;
        while (lo < hi) { int mid = (lo + hi) >> 1; if (batch[mid] < g) lo = mid + 1; else hi = mid; }
        s_se[0] = lo;
        lo = 0; hi = N;
        while (lo < hi) { int mid = (lo + hi) >> 1; if (batch[mid] < g + 1) lo = mid + 1; else hi = mid; }
        s_se[1] = lo;
    }
    __syncthreads();
    float cntf = (float)(s_se[1] - s_se[0]);
    int c = threadIdx.x;
    out[g * NFEAT + c] = sums[g * NFEAT + c] / fmaxf(cntf, 1.f);
}

// ---------------- launch ----------------

static inline size_t align_up(size_t x, size_t a) { return (x + a - 1) & ~(a - 1); }

extern "C" void kernel_launch(void* const* d_in, const int* in_sizes, int n_in,
                              void* d_out, int out_size, void* d_ws, size_t ws_size,
                              hipStream_t stream) {
    const float* x = (const float*)d_in[0];
    const int* edge_index = (const int*)d_in[1];
    const int* batch = (const int*)d_in[2];

    const int N = in_sizes[2];          // 50000
    const int E = in_sizes[1] / 2;      // 1600000
    const int G = out_size / NFEAT;     // 64

    const int* e_src = edge_index;
    const int* e_dst = edge_index + E;

    const float* W[3]; const float* bP[3]; const float* gP[3];
    const float* beP[3]; const float* mP[3]; const float* vP[3];
    for (int i = 0; i < 3; i++) {
        W[i]  = (const float*)d_in[3 + 6 * i + 0];
        bP[i] = (const float*)d_in[3 + 6 * i + 1];
        gP[i] = (const float*)d_in[3 + 6 * i + 2];
        beP[i]= (const float*)d_in[3 + 6 * i + 3];
        mP[i] = (const float*)d_in[3 + 6 * i + 4];
        vP[i] = (const float*)d_in[3 + 6 * i + 5];
    }

    // workspace carve-up
    char* ws = (char*)d_ws;
    size_t off = 0;
    auto carve = [&](size_t bytes) { void* p = ws + off; off = align_up(off + bytes, 256); return p; };
    int*   cnt      = (int*)  carve((size_t)N * 4);
    int*   cursor   = (int*)  carve((size_t)N * 4);
    int*   row_ptr  = (int*)  carve((size_t)N * 4);
    int*   blk_sums = (int*)  carve(1024);
    float* dinv     = (float*)carve((size_t)N * 4);
    int*   csr_src  = (int*)  carve((size_t)E * 4);
    float* agg3     = (float*)carve((size_t)N * 3 * 4);
    unsigned short* bufA = (unsigned short*)carve((size_t)N * NFEAT * 2);
    unsigned short* bufB = (unsigned short*)carve((size_t)N * NFEAT * 2);
    unsigned short* Wt1  = (unsigned short*)carve((size_t)NFEAT * NFEAT * 2);
    unsigned short* Wt2  = (unsigned short*)carve((size_t)NFEAT * NFEAT * 2);
    float* psums    = (float*)carve((size_t)G * NFEAT * 4);
    (void)ws_size;

    hipMemsetAsync(cnt, 0, (size_t)N * 4, stream);
    hipMemsetAsync(cursor, 0, (size_t)N * 4, stream);
    hipMemsetAsync(psums, 0, (size_t)G * NFEAT * 4, stream);

    const int BS = 256;
    // degree + CSR
    k_count<<<(E + BS - 1) / BS, BS, 0, stream>>>(e_dst, cnt, E);
    k_dinv<<<(N + BS - 1) / BS, BS, 0, stream>>>(cnt, dinv, N);
    int nb = (N + SCAN_BS - 1) / SCAN_BS;
    k_scan_block<<<nb, SCAN_BS, 0, stream>>>(cnt, row_ptr, blk_sums, N);
    k_scan_bsums<<<1, 64, 0, stream>>>(blk_sums, nb);
    k_scan_add<<<(N + BS - 1) / BS, BS, 0, stream>>>(row_ptr, blk_sums, N);
    k_fill<<<(E + BS - 1) / BS, BS, 0, stream>>>(e_src, e_dst, row_ptr, cursor, csr_src, E);

    // weight prep (bf16 + transpose)
    k_wconv<<<NFEAT, NFEAT, 0, stream>>>(W[1], Wt1);
    k_wconv<<<NFEAT, NFEAT, 0, stream>>>(W[2], Wt2);

    // layer 0: propagate(x) [width 3] then 3->256 matmul + BN + ReLU -> bf16
    k_agg3<<<(N + 63) / 64, 64, 0, stream>>>(x, csr_src, row_ptr, cnt, dinv, agg3, N);
    k_m0<<<N, NFEAT, 0, stream>>>(agg3, W[0], bP[0], gP[0], beP[0], mP[0], vP[0], bufA, N);

    dim3 mmGrid((N + 127) / 128, 2);
    // layer 1: h@W1 (MFMA) -> propagate -> BN + ReLU
    k_mm_mfma<<<mmGrid, 256, 0, stream>>>(bufA, Wt1, bufB, N);
    k_agg256b<true><<<N, 64, 0, stream>>>(bufB, csr_src, row_ptr, cnt, dinv,
                                          bP[1], gP[1], beP[1], mP[1], vP[1], bufA);
    // layer 2: h@W2 (MFMA) -> propagate -> BN (no ReLU)
    k_mm_mfma<<<mmGrid, 256, 0, stream>>>(bufA, Wt2, bufB, N);
    k_agg256b<false><<<N, 64, 0, stream>>>(bufB, csr_src, row_ptr, cnt, dinv,
                                           bP[2], gP[2], beP[2], mP[2], vP[2], bufA);

    // pool: parallel two-stage
    int pb = (N + PNODES - 1) / PNODES;
    k_pool_partial<<<pb, NFEAT, 0, stream>>>(bufA, batch, psums, N);
    k_pool_final<<<G, NFEAT, 0, stream>>>(psums, batch, (float*)d_out, N);
}